// Round 10
// baseline (9013.345 us; speedup 1.0000x reference)
//
#include <hip/hip_runtime.h>
#include <stdint.h>

#define T_LEN 4096
#define HID   400
#define G4    1600
#define KDIM  300
#define STACKN 32

__device__ __forceinline__ float fsig(float x){ return 1.f/(1.f + __expf(-x)); }
__device__ __forceinline__ float ftanh(float x){ float e = __expf(2.f*x); return 1.f - 2.f/(e+1.f); }

// Single-load tag spin (R4-proven; R8 showed extra in-flight polls regress via contention).
__device__ __forceinline__ float wait_tag(const unsigned long long* p, unsigned want){
  unsigned long long ex;
  do { ex = __hip_atomic_load(p, __ATOMIC_RELAXED, __HIP_MEMORY_SCOPE_AGENT); }
  while ((unsigned)(ex >> 32) != want);
  union{unsigned u; float f;} c; c.u = (unsigned)ex; return c.f;
}
__device__ __forceinline__ void pub_tag(unsigned long long* p, unsigned tag, float v){
  union{unsigned u; float f;} c; c.f = v;
  __hip_atomic_store(p, ((unsigned long long)tag << 32) | (unsigned long long)c.u,
                     __ATOMIC_RELAXED, __HIP_MEMORY_SCOPE_AGENT);
}
// LDS-only workgroup barrier (R9-verified correct): no vmcnt drain.
__device__ __forceinline__ void bar(){
  asm volatile("s_waitcnt lgkmcnt(0)\n\ts_barrier" ::: "memory");
}

// ---------------- layer-0 xg GEMM with fused embedding gather (K=150, f32) ----------------
__global__ void __launch_bounds__(256) kgemm0(
    const int* __restrict__ xma, const int* __restrict__ xcpc, const int* __restrict__ xr,
    const float* __restrict__ em, const float* __restrict__ ec, const float* __restrict__ er,
    const float* __restrict__ W, const float* __restrict__ b1, const float* __restrict__ b2,
    float* __restrict__ XG)
{
  __shared__ float xs[8*152];
  const int t0 = blockIdx.x*8;
  const int tid = threadIdx.x;
  for (int idx = tid; idx < 8*150; idx += 256){
    int tt = idx / 150, k = idx - tt*150;
    int t = t0 + tt;
    float v;
    if (k < 50)       v = em[(size_t)xma[t]*50 + k];
    else if (k < 100) v = ec[(size_t)xcpc[t]*50 + (k-50)];
    else              v = er[(size_t)xr[t]*50 + (k-100)];
    xs[tt*152 + k] = v;
  }
  __syncthreads();
  int r = blockIdx.y*256 + tid;
  if (r >= G4) return;
  float acc[8];
  #pragma unroll
  for (int i=0;i<8;i++) acc[i]=0.f;
  const float2* wr = (const float2*)(W + (size_t)r*150);
  for (int k2=0;k2<75;k2++){
    float2 w = wr[k2];
    int k = 2*k2;
    #pragma unroll
    for (int tt=0;tt<8;tt++)
      acc[tt] += w.x*xs[tt*152+k] + w.y*xs[tt*152+k+1];
  }
  float bb = b1[r] + b2[r];
  #pragma unroll
  for (int tt=0;tt<8;tt++)
    XG[(size_t)(t0+tt)*G4 + r] = acc[tt] + bb;
}

// ================== fused 2-layer pipelined LSTM scan ==================
// 48 WGs: [0,16) L0 recurrence; [16,32) FF (xg1 = Wih1 @ h0_t + biases); [32,48) L1 recurrence.
// Handshake identical to R4/R9 (single-load tagged spin, depth-8 slots, relaxed agent atomics).
// NEW vs R9 (within-WG only):
//  - matvec: 2 rows/lane, wave-uniform k-slice (part = wave, waves 0..3). 100 pure-broadcast
//    ds_read_b128 per WG/step instead of 200 multi-address ones; no shuffle reduction.
//  - 2 barriers/step (was 3): lds_h double-buffered; epilogue writes own slice directly
//    into the next buffer. L1's lds_xg double-buffered for the same reason.
//  - L1 polls xg (always already published) BEFORE the h1 recurrence wait.
__global__ void __launch_bounds__(512,1) kpipe(
    const float* __restrict__ XG0,
    const float* __restrict__ Whh0, const float* __restrict__ Whh1,
    const float* __restrict__ Wih1, const float* __restrict__ bih1,
    const float* __restrict__ bhh1,
    float* __restrict__ RN,
    unsigned long long* hbufA, unsigned long long* hbufB,
    unsigned long long* gbuf, int T)
{
  const int wid  = blockIdx.x;
  const int tid  = threadIdx.x;
  const int wave = tid >> 6;
  const int lane = tid & 63;
  const bool domat = (wave < 4) && (lane < 50);

  __shared__ float lds_h[2][400];
  __shared__ float lds_part[400];
  __shared__ float lds_xg[2][100];

  // matvec row mapping (rows are gate-rows 0..99 = gate*25 + jj)
  const int r0 = 2*lane, r1 = 2*lane + 1;
  const int g0 = r0/25, j0 = r0%25;
  const int g1 = r1/25, j1 = r1%25;

  if (wid < 16){
    // ---------------- layer-0 recurrence ----------------
    const int w = wid;
    const int base25 = w*25;
    float4 wa[25], wb[25];
    if (domat){
      const float4* p0 = (const float4*)(Whh0 + (size_t)(g0*400 + base25 + j0)*HID) + wave*25;
      const float4* p1 = (const float4*)(Whh0 + (size_t)(g1*400 + base25 + j1)*HID) + wave*25;
      #pragma unroll
      for (int i=0;i<25;i++){ wa[i]=p0[i]; wb[i]=p1[i]; }
    }
    const int j = base25 + tid;              // valid tid<25
    float c = 0.f;
    for (int t=0; t<T; t++){
      float xgi=0,xgf=0,xgg=0,xgo=0;
      if (tid < 25){
        const float* xrw = XG0 + (size_t)t*G4;
        xgi=xrw[j]; xgf=xrw[400+j]; xgg=xrw[800+j]; xgo=xrw[1200+j];
      }
      if (tid < 400){
        bool own = (tid >= base25) && (tid < base25+25);
        if (!own){
          float hv = (t>0) ? wait_tag(hbufA + (size_t)(t&7)*HID + tid, (unsigned)t) : 0.f;
          lds_h[t&1][tid] = hv;
        } else if (t == 0){
          lds_h[0][tid] = 0.f;               // epilogue(t-1) writes own for t>0
        }
      }
      bar();
      if (domat){
        const float4* hp = (const float4*)(&lds_h[t&1][wave*100]);
        float a0=0.f, a1=0.f;
        #pragma unroll
        for (int i=0;i<25;i++){
          float4 h4 = hp[i];
          a0 += wa[i].x*h4.x + wa[i].y*h4.y + wa[i].z*h4.z + wa[i].w*h4.w;
          a1 += wb[i].x*h4.x + wb[i].y*h4.y + wb[i].z*h4.z + wb[i].w*h4.w;
        }
        *(float2*)&lds_part[wave*100 + r0] = make_float2(a0, a1);
      }
      bar();
      if (tid < 25){
        float s0 = lds_part[tid]    + lds_part[100+tid]    + lds_part[200+tid]    + lds_part[300+tid];
        float s1 = lds_part[25+tid] + lds_part[125+tid]    + lds_part[225+tid]    + lds_part[325+tid];
        float s2 = lds_part[50+tid] + lds_part[150+tid]    + lds_part[250+tid]    + lds_part[350+tid];
        float s3 = lds_part[75+tid] + lds_part[175+tid]    + lds_part[275+tid]    + lds_part[375+tid];
        float gi = xgi+s0, gf = xgf+s1, gg = xgg+s2, go = xgo+s3;
        c = fsig(gf)*c + fsig(gi)*ftanh(gg);
        float h = fsig(go)*ftanh(c);
        pub_tag(hbufA + (size_t)((t+1)&7)*HID + j, (unsigned)(t+1), h);
        lds_h[(t+1)&1][j] = h;               // own slice for next step (replaces bar3)
      }
    }
  } else if (wid < 32){
    // ---------------- FF: xg1 = Wih1 @ h0_t + biases ----------------
    const int f = wid - 16;
    const int base25 = f*25;
    float4 wa[25], wb[25];
    if (domat){
      const float4* p0 = (const float4*)(Wih1 + (size_t)(g0*400 + base25 + j0)*HID) + wave*25;
      const float4* p1 = (const float4*)(Wih1 + (size_t)(g1*400 + base25 + j1)*HID) + wave*25;
      #pragma unroll
      for (int i=0;i<25;i++){ wa[i]=p0[i]; wb[i]=p1[i]; }
    }
    float bias = 0.f; int grow = 0;
    if (tid < 100){
      grow = (tid/25)*400 + base25 + (tid%25);
      bias = bih1[grow] + bhh1[grow];
    }
    for (int t=0; t<T; t++){
      if (tid < 400)
        lds_h[0][tid] = wait_tag(hbufA + (size_t)((t+1)&7)*HID + tid, (unsigned)(t+1));
      bar();
      if (domat){
        const float4* hp = (const float4*)(&lds_h[0][wave*100]);
        float a0=0.f, a1=0.f;
        #pragma unroll
        for (int i=0;i<25;i++){
          float4 h4 = hp[i];
          a0 += wa[i].x*h4.x + wa[i].y*h4.y + wa[i].z*h4.z + wa[i].w*h4.w;
          a1 += wb[i].x*h4.x + wb[i].y*h4.y + wb[i].z*h4.z + wb[i].w*h4.w;
        }
        *(float2*)&lds_part[wave*100 + r0] = make_float2(a0, a1);
      }
      bar();
      if (tid < 100){
        float s = lds_part[tid] + lds_part[100+tid] + lds_part[200+tid] + lds_part[300+tid];
        pub_tag(gbuf + (size_t)((t+1)&7)*G4 + grow, (unsigned)(t+1), s + bias);
      }
    }
  } else {
    // ---------------- layer-1 recurrence ----------------
    const int l = wid - 32;
    const int base25 = l*25;
    float4 wa[25], wb[25];
    if (domat){
      const float4* p0 = (const float4*)(Whh1 + (size_t)(g0*400 + base25 + j0)*HID) + wave*25;
      const float4* p1 = (const float4*)(Whh1 + (size_t)(g1*400 + base25 + j1)*HID) + wave*25;
      #pragma unroll
      for (int i=0;i<25;i++){ wa[i]=p0[i]; wb[i]=p1[i]; }
    }
    const int j = base25 + tid;              // valid tid<25
    float c = 0.f;
    for (int t=0; t<T; t++){
      // xg staging FIRST: FF runs ahead, tags already present -> 1 quick round,
      // hidden under the h1 recurrence wait below (R4 had it after the h spin).
      if (tid >= 400 && tid < 500){
        int x = tid - 400;
        int xgrow = (x/25)*400 + base25 + (x%25);
        lds_xg[t&1][x] = wait_tag(gbuf + (size_t)((t+1)&7)*G4 + xgrow, (unsigned)(t+1));
      }
      if (tid < 400){
        bool own = (tid >= base25) && (tid < base25+25);
        if (!own){
          float hv = (t>0) ? wait_tag(hbufB + (size_t)(t&7)*HID + tid, (unsigned)t) : 0.f;
          lds_h[t&1][tid] = hv;
        } else if (t == 0){
          lds_h[0][tid] = 0.f;
        }
      }
      bar();
      if (domat){
        const float4* hp = (const float4*)(&lds_h[t&1][wave*100]);
        float a0=0.f, a1=0.f;
        #pragma unroll
        for (int i=0;i<25;i++){
          float4 h4 = hp[i];
          a0 += wa[i].x*h4.x + wa[i].y*h4.y + wa[i].z*h4.z + wa[i].w*h4.w;
          a1 += wb[i].x*h4.x + wb[i].y*h4.y + wb[i].z*h4.z + wb[i].w*h4.w;
        }
        *(float2*)&lds_part[wave*100 + r0] = make_float2(a0, a1);
      }
      bar();
      if (tid < 25){
        float s0 = lds_part[tid]    + lds_part[100+tid] + lds_part[200+tid] + lds_part[300+tid];
        float s1 = lds_part[25+tid] + lds_part[125+tid] + lds_part[225+tid] + lds_part[325+tid];
        float s2 = lds_part[50+tid] + lds_part[150+tid] + lds_part[250+tid] + lds_part[350+tid];
        float s3 = lds_part[75+tid] + lds_part[175+tid] + lds_part[275+tid] + lds_part[375+tid];
        float gi = lds_xg[t&1][tid]    + s0;
        float gf = lds_xg[t&1][25+tid] + s1;
        float gg = lds_xg[t&1][50+tid] + s2;
        float go = lds_xg[t&1][75+tid] + s3;
        c = fsig(gf)*c + fsig(gi)*ftanh(gg);
        float h = fsig(go)*ftanh(c);
        RN[(size_t)t*HID + j] = h;
        pub_tag(hbufB + (size_t)((t+1)&7)*HID + j, (unsigned)(t+1), h);
        lds_h[(t+1)&1][j] = h;
      }
    }
  }
}

// ---------------- rtoken = RN @ fcW.T + fcb  (f32) ----------------
__global__ void __launch_bounds__(256) krtoken(
    const float* __restrict__ RN, const float* __restrict__ fcW,
    const float* __restrict__ fcb, float* __restrict__ out)
{
  __shared__ float xs[8*400];
  const int t0 = blockIdx.x*8;
  const int tid = threadIdx.x;
  for (int idx = tid; idx < 8*400; idx += 256)
    xs[idx] = RN[(size_t)t0*400 + idx];
  __syncthreads();
  if (tid >= 150) return;
  float acc[8];
  #pragma unroll
  for (int i=0;i<8;i++) acc[i]=0.f;
  const float4* wr = (const float4*)(fcW + (size_t)tid*400);
  for (int k4=0;k4<100;k4++){
    float4 w = wr[k4];
    #pragma unroll
    for (int tt=0;tt<8;tt++){
      const float4 x4 = *(const float4*)(xs + tt*400 + 4*k4);
      acc[tt] += w.x*x4.x + w.y*x4.y + w.z*x4.z + w.w*x4.w;
    }
  }
  float bb = fcb[tid];
  #pragma unroll
  for (int tt=0;tt<8;tt++)
    out[(size_t)(t0+tt)*150 + tid] = acc[tt] + bb;
}

// ---------------- per-t context scalar ----------------
__global__ void kfinal(const float* __restrict__ RN, const float* __restrict__ actW,
                       const float* __restrict__ actb, const float* __restrict__ Dp,
                       float* __restrict__ vbuf)
{
  int t = blockIdx.x, l = threadIdx.x;
  const float* r = RN + (size_t)t*HID;
  float s0=0.f, s1=0.f, s2=0.f, sd=0.f;
  for (int k=l; k<HID; k+=64){
    float rv = r[k];
    s0 += actW[k]*rv;
    s1 += actW[400+k]*rv;
    s2 += actW[800+k]*rv;
    sd += Dp[k]*rv;
  }
  #pragma unroll
  for (int o=1;o<64;o<<=1){
    s0 += __shfl_xor(s0,o); s1 += __shfl_xor(s1,o);
    s2 += __shfl_xor(s2,o); sd += __shfl_xor(sd,o);
  }
  if (l==0){
    s0 += actb[0]; s1 += actb[1]; s2 += actb[2];
    float m = fmaxf(s0, fmaxf(s1, s2));
    float e0 = __expf(s0-m), e1 = __expf(s1-m), e2 = __expf(s2-m);
    float p0 = e0/(e0+e1+e2);
    vbuf[t] = p0 * fsig(sd);
  }
}

// ---------------- context write: zero + slot0 broadcast (f32). LAST kernel. ----------------
__global__ void kctx(const float* __restrict__ vbuf, uint4* __restrict__ ctx, int n16){
  int i = blockIdx.x*256 + threadIdx.x;
  int stride = gridDim.x*256;
  for (; i<n16; i+=stride){
    int t = i / 3200;
    int p = i - t*3200;
    uint4 z;
    if (p < 100){
      float v = vbuf[t];
      union{float f; uint32_t u;} cv; cv.f = v;
      z.x = z.y = z.z = z.w = cv.u;
    } else {
      z.x = z.y = z.z = z.w = 0u;
    }
    ctx[i] = z;
  }
}

// ---------------- key LSTM (1 step, h0=c0=0 so key_Whh is dead) + fc (f32) ----------------
__global__ void __launch_bounds__(512) kkey(
    const float* __restrict__ RN, const float* __restrict__ Wih,
    const float* __restrict__ bih, const float* __restrict__ bhh,
    const float* __restrict__ fcW, const float* __restrict__ fcb,
    float* __restrict__ out)
{
  __shared__ float rh[HID];
  __shared__ float gk[4*KDIM];
  __shared__ float hk[KDIM];
  int tid = threadIdx.x;
  if (tid < HID) rh[tid] = RN[(size_t)(T_LEN-1)*HID + tid];
  __syncthreads();
  for (int r = tid; r < 4*KDIM; r += 512){
    const float4* wr = (const float4*)(Wih + (size_t)r*HID);
    float acc = 0.f;
    for (int k4=0;k4<100;k4++){
      float4 w = wr[k4];
      const float4 x4 = *(const float4*)(rh + 4*k4);
      acc += w.x*x4.x + w.y*x4.y + w.z*x4.z + w.w*x4.w;
    }
    gk[r] = acc + bih[r] + bhh[r];
  }
  __syncthreads();
  if (tid < KDIM){
    float gi = gk[tid], gg = gk[2*KDIM+tid], go = gk[3*KDIM+tid];
    float cc = fsig(gi)*ftanh(gg);
    hk[tid] = fsig(go)*ftanh(cc);
  }
  __syncthreads();
  if (tid < HID){
    const float4* wr = (const float4*)(fcW + (size_t)tid*KDIM);
    float acc = 0.f;
    for (int k4=0;k4<75;k4++){
      float4 w = wr[k4];
      const float4 x4 = *(const float4*)(hk + 4*k4);
      acc += w.x*x4.x + w.y*x4.y + w.z*x4.z + w.w*x4.w;
    }
    out[tid] = acc + fcb[tid];
  }
}

extern "C" void kernel_launch(void* const* d_in, const int* in_sizes, int n_in,
                              void* d_out, int out_size, void* d_ws, size_t ws_size,
                              hipStream_t stream)
{
  (void)in_sizes; (void)n_in; (void)ws_size;
  const int*   xr   = (const int*)d_in[0];
  const int*   xcpc = (const int*)d_in[1];
  const int*   xma  = (const int*)d_in[2];
  const float* em   = (const float*)d_in[3];
  const float* ec   = (const float*)d_in[4];
  const float* er   = (const float*)d_in[5];
  const float* Wih0 = (const float*)d_in[6];
  const float* Whh0 = (const float*)d_in[7];
  const float* bih0 = (const float*)d_in[8];
  const float* bhh0 = (const float*)d_in[9];
  const float* Wih1 = (const float*)d_in[10];
  const float* Whh1 = (const float*)d_in[11];
  const float* bih1 = (const float*)d_in[12];
  const float* bhh1 = (const float*)d_in[13];
  const float* fcW  = (const float*)d_in[14];
  const float* fcb  = (const float*)d_in[15];
  const float* actW = (const float*)d_in[16];
  const float* actb = (const float*)d_in[17];
  const float* Dp   = (const float*)d_in[18];
  const float* kWih = (const float*)d_in[19];
  /* d_in[20] key_Whh unused: h0 = 0 for the single key step */
  const float* kbih = (const float*)d_in[21];
  const float* kbhh = (const float*)d_in[22];
  const float* kfcW = (const float*)d_in[23];
  const float* kfcb = (const float*)d_in[24];

  float* vbuf = (float*)d_ws;                           // 16 KB in ws

  // ---- large scratch + handshake bufs in TAIL of d_out's ctx region; kctx rewrites last ----
  float* out = (float*)d_out;
  char*  ob  = (char*)d_out;
  size_t total = (size_t)out_size * 4;                  // 212,174,400 bytes
  float* XG0 = (float*)(ob + total - 26214400);         // 4096*1600 f32
  float* RN  = (float*)(ob + total - 32768000);         // 4096*400 f32
  char*  ctl = ob + total - 32768000 - 262144;          // control block (256 KB reserve)
  unsigned long long* hbufA = (unsigned long long*)(ctl);            // 8*400*8 = 25,600 B
  unsigned long long* hbufB = (unsigned long long*)(ctl + 25600);    // 25,600 B
  unsigned long long* gbuf  = (unsigned long long*)(ctl + 51200);    // 8*1600*8 = 102,400 B

  float* rtok = out;                 // 4096*150
  float* ktok = out + 614400;        // 400
  uint4* ctxp = (uint4*)(ob + 614800u*4u);              // ctx region, 209,715,200 B
  int n16 = (int)((total - 614800u*4u) >> 4);           // 13,107,200

  dim3 gg(T_LEN/8, 7);
  kgemm0<<<gg,256,0,stream>>>(xma, xcpc, xr, em, ec, er, Wih0, bih0, bhh0, XG0);
  kpipe<<<48,512,0,stream>>>(XG0, Whh0, Whh1, Wih1, bih1, bhh1, RN,
                             hbufA, hbufB, gbuf, T_LEN);
  krtoken<<<T_LEN/8,256,0,stream>>>(RN, fcW, fcb, rtok);
  kkey<<<1,512,0,stream>>>(RN, kWih, kbih, kbhh, kfcW, kfcb, ktok);
  kfinal<<<T_LEN,64,0,stream>>>(RN, actW, actb, Dp, vbuf);
  kctx<<<2048,256,0,stream>>>(vbuf, ctxp, n16);
}